// Round 5
// baseline (724.630 us; speedup 1.0000x reference)
//
#include <hip/hip_runtime.h>

#define D 64
#define NEG_INF -9e15f
#define MAXK 16
#define BSH 7                 // bucket = 128 rows
#define BROWS 128
#define MAXNB 1024
#define SCAP 7936             // LDS sort capacity (edges); bucket mean 6827, sigma 83

// ---------- Phase 0: relation-space precompute ----------
__global__ void relpre_kernel(const float* __restrict__ fc_W, const float* __restrict__ fc_b,
                              const float* __restrict__ rel_emb,
                              float* __restrict__ w1r, float* __restrict__ w2r,
                              float* __restrict__ br) {
    int r = blockIdx.x;
    int j = threadIdx.x;
    const float* rr = rel_emb + r * D;
    float s1 = 0.f, s2 = 0.f;
    for (int d = 0; d < D; ++d) {
        float rv = rr[d];
        s1 += fc_W[j * D + d] * rv;
        s2 += fc_W[(D + j) * D + d] * rv;
    }
    w1r[r * D + j] = s1;
    w2r[r * D + j] = s2;
    if (j == 0) {
        float sb = 0.f;
        for (int d = 0; d < D; ++d) sb += fc_b[d] * rr[d];
        br[r] = sb;
    }
}

// ---------- Phase 1: GAT item embeddings (one wave per item) ----------
__global__ void gat_kernel(const float* __restrict__ item_emb, const float* __restrict__ ent_emb,
                           const int* __restrict__ kg_e, const int* __restrict__ kg_r,
                           const float* __restrict__ w1r, const float* __restrict__ w2r,
                           const float* __restrict__ br,
                           float* __restrict__ x_items, int I, int K, int pad_id) {
    int wave = (blockIdx.x * blockDim.x + threadIdx.x) >> 6;
    int lane = threadIdx.x & 63;
    if (wave >= I) return;
    int i = wave;
    float itemv = item_emb[i * D + lane];
    float entv[MAXK];
    float e[MAXK];
    for (int k = 0; k < K; ++k) {
        int eidx = kg_e[i * K + k];
        int r = kg_r[i * K + k];
        float ev = ent_emb[(long)eidx * D + lane];
        entv[k] = ev;
        float p = itemv * w1r[r * D + lane] + ev * w2r[r * D + lane];
        #pragma unroll
        for (int off = 32; off > 0; off >>= 1) p += __shfl_xor(p, off, 64);
        p += br[r];
        p = p > 0.f ? p : 0.2f * p;
        if (eidx == pad_id) p = NEG_INF;
        e[k] = p;
    }
    float m = e[0];
    for (int k = 1; k < K; ++k) m = fmaxf(m, e[k]);
    float s = 0.f;
    float att[MAXK];
    for (int k = 0; k < K; ++k) { att[k] = expf(e[k] - m); s += att[k]; }
    float inv = 1.f / s;
    float o = itemv;
    for (int k = 0; k < K; ++k) o += att[k] * inv * entv[k];
    x_items[(long)i * D + lane] = o;
}

// ---------- init (deferred mode): copy user_emb -> x0 user half ----------
__global__ void copyu_kernel(const float* __restrict__ src, float* __restrict__ dst, int n4) {
    int i = blockIdx.x * blockDim.x + threadIdx.x;
    if (i < n4) ((float4*)dst)[i] = ((const float4*)src)[i];
}

// ---------- init (legacy mode): x users + acc = x ----------
__global__ void init_kernel(const float* __restrict__ user_emb,
                            float* __restrict__ x, float* __restrict__ acc,
                            int UD, int ND) {
    for (int idx = blockIdx.x * blockDim.x + threadIdx.x; idx < ND;
         idx += gridDim.x * blockDim.x) {
        float v = (idx < UD) ? user_emb[idx] : x[idx];
        x[idx] = v;
        acc[idx] = v;
    }
}

// ---------- Bucket histogram (LDS-staged) ----------
__global__ void bhist_kernel(const int* __restrict__ rows, int* __restrict__ bcnt,
                             int n_edges, int NB) {
    __shared__ int h[MAXNB];
    for (int i = threadIdx.x; i < NB; i += blockDim.x) h[i] = 0;
    __syncthreads();
    for (int e = blockIdx.x * blockDim.x + threadIdx.x; e < n_edges;
         e += gridDim.x * blockDim.x)
        atomicAdd(&h[rows[e] >> BSH], 1);
    __syncthreads();
    for (int i = threadIdx.x; i < NB; i += blockDim.x)
        if (h[i]) atomicAdd(&bcnt[i], h[i]);
}

// ---------- Bucket scan (single block; NB <= 1024) ----------
__global__ void bscan_kernel(const int* __restrict__ bcnt, int* __restrict__ bstart,
                             int* __restrict__ bfill, int NB, int n_edges) {
    __shared__ int tmp[MAXNB];
    int tid = threadIdx.x;
    int v = (tid < NB) ? bcnt[tid] : 0;
    tmp[tid] = v;
    __syncthreads();
    for (int off = 1; off < MAXNB; off <<= 1) {
        int t = (tid >= off) ? tmp[tid - off] : 0;
        __syncthreads();
        tmp[tid] += t;
        __syncthreads();
    }
    if (tid < NB) {
        int ex = tmp[tid] - v;
        bstart[tid] = ex;
        bfill[tid] = ex;
    }
    if (tid == 0) bstart[NB] = n_edges;
}

// ---------- Partition: per-block hist -> segment reserve -> direct write ----------
// etmp[pos] = (valbits<<32) | (row&127)<<20 | col
__global__ void part_kernel(const int* __restrict__ rows, const int* __restrict__ cols,
                            const float* __restrict__ vals,
                            int* __restrict__ bfill, long* __restrict__ etmp,
                            int n_edges, int NB) {
    __shared__ int h[MAXNB];
    __shared__ int base[MAXNB];
    __shared__ int off[MAXNB];
    int nb_blocks = gridDim.x;
    int c0 = (int)((long)n_edges * blockIdx.x / nb_blocks);
    int c1 = (int)((long)n_edges * (blockIdx.x + 1) / nb_blocks);
    for (int i = threadIdx.x; i < NB; i += blockDim.x) { h[i] = 0; off[i] = 0; }
    __syncthreads();
    for (int e = c0 + threadIdx.x; e < c1; e += blockDim.x)
        atomicAdd(&h[rows[e] >> BSH], 1);
    __syncthreads();
    for (int i = threadIdx.x; i < NB; i += blockDim.x)
        if (h[i]) base[i] = atomicAdd(&bfill[i], h[i]);
    __syncthreads();
    for (int e = c0 + threadIdx.x; e < c1; e += blockDim.x) {
        int r = rows[e];
        int b = r >> BSH;
        int pos = base[b] + atomicAdd(&off[b], 1);
        long pv = ((long)(unsigned)__float_as_int(vals[e]) << 32)
                | (unsigned)(cols[e] | ((r & (BROWS - 1)) << 20));
        __builtin_nontemporal_store(pv, &etmp[pos]);
    }
}

// ---------- In-bucket counting sort -> exact CSR ----------
// Two-pass over the bucket segment (2nd read is L2-hot); scatter goes through
// LDS so global writes are fully coalesced. Fallback to global scatter if the
// bucket exceeds SCAP (13 sigma above mean -> effectively never).
__global__ __launch_bounds__(256) void
sort_kernel(const long* __restrict__ etmp, const int* __restrict__ bstart,
            long* __restrict__ edges, int* __restrict__ row_start,
            int* __restrict__ cnt, int N) {
    __shared__ long obuf[SCAP];
    __shared__ int h[BROWS];
    __shared__ int excl[BROWS];
    __shared__ int off[BROWS];
    int b = blockIdx.x;
    int s = bstart[b];
    int t = bstart[b + 1];
    int m = t - s;
    int tid = threadIdx.x;
    if (tid < BROWS) { h[tid] = 0; off[tid] = 0; }
    __syncthreads();
    for (int i = tid; i < m; i += 256)
        atomicAdd(&h[((int)etmp[s + i] >> 20) & (BROWS - 1)], 1);
    __syncthreads();
    if (tid < BROWS) excl[tid] = h[tid];
    __syncthreads();
    for (int o = 1; o < BROWS; o <<= 1) {
        int v = (tid < BROWS && tid >= o) ? excl[tid - o] : 0;
        __syncthreads();
        if (tid < BROWS) excl[tid] += v;
        __syncthreads();
    }
    int row0 = b << BSH;
    if (tid < BROWS) {
        int ex = excl[tid] - h[tid];       // exclusive
        excl[tid] = ex;
        int row = row0 + tid;
        if (row < N) { row_start[row] = s + ex; cnt[row] = h[tid]; }
    }
    __syncthreads();
    if (m <= SCAP) {
        for (int i = tid; i < m; i += 256) {
            long v = etmp[s + i];          // L2-hot second read
            int r = ((int)v >> 20) & (BROWS - 1);
            int pos = excl[r] + atomicAdd(&off[r], 1);
            obuf[pos] = (v & ~0xFFFFFFFFL) | (unsigned)((unsigned)v & 0xFFFFFu);
        }
        __syncthreads();
        for (int i = tid; i < m; i += 256) edges[s + i] = obuf[i];
    } else {
        for (int i = tid; i < m; i += 256) {
            long v = etmp[s + i];
            int r = ((int)v >> 20) & (BROWS - 1);
            int pos = s + excl[r] + atomicAdd(&off[r], 1);
            edges[pos] = (v & ~0xFFFFFFFFL) | (unsigned)((unsigned)v & 0xFFFFFu);
        }
    }
}

// ---------- Phase 2b: CSR SpMV, one wave per row ----------
// nt loads for the edge stream / nt store for nxt keep L2 reserved for the
// x-row gathers. acc != nullptr selects legacy RMW mode.
__global__ __launch_bounds__(256) void
spmv_kernel(const long* __restrict__ edges, const int* __restrict__ row_start,
            const int* __restrict__ cnt, const float* __restrict__ x,
            float* __restrict__ nxt, float* __restrict__ acc, int N) {
    long gid = (long)blockIdx.x * blockDim.x + threadIdx.x;
    int row = (int)(gid >> 6);
    int lane = (int)(gid & 63);
    if (row >= N) return;
    int s = row_start[row];
    int n = cnt[row];
    const long* ep = edges + s;
    float sum = 0.f;
    int e = 0;
    for (; e + 8 <= n; e += 8) {
        long q0 = __builtin_nontemporal_load(ep + e);
        long q1 = __builtin_nontemporal_load(ep + e + 1);
        long q2 = __builtin_nontemporal_load(ep + e + 2);
        long q3 = __builtin_nontemporal_load(ep + e + 3);
        long q4 = __builtin_nontemporal_load(ep + e + 4);
        long q5 = __builtin_nontemporal_load(ep + e + 5);
        long q6 = __builtin_nontemporal_load(ep + e + 6);
        long q7 = __builtin_nontemporal_load(ep + e + 7);
        float g0 = x[(long)((int)q0 & 0xFFFFF) * D + lane];
        float g1 = x[(long)((int)q1 & 0xFFFFF) * D + lane];
        float g2 = x[(long)((int)q2 & 0xFFFFF) * D + lane];
        float g3 = x[(long)((int)q3 & 0xFFFFF) * D + lane];
        float g4 = x[(long)((int)q4 & 0xFFFFF) * D + lane];
        float g5 = x[(long)((int)q5 & 0xFFFFF) * D + lane];
        float g6 = x[(long)((int)q6 & 0xFFFFF) * D + lane];
        float g7 = x[(long)((int)q7 & 0xFFFFF) * D + lane];
        sum += __int_as_float((int)(q0 >> 32)) * g0;
        sum += __int_as_float((int)(q1 >> 32)) * g1;
        sum += __int_as_float((int)(q2 >> 32)) * g2;
        sum += __int_as_float((int)(q3 >> 32)) * g3;
        sum += __int_as_float((int)(q4 >> 32)) * g4;
        sum += __int_as_float((int)(q5 >> 32)) * g5;
        sum += __int_as_float((int)(q6 >> 32)) * g6;
        sum += __int_as_float((int)(q7 >> 32)) * g7;
    }
    for (; e < n; ++e) {
        long q = __builtin_nontemporal_load(ep + e);
        sum += __int_as_float((int)(q >> 32)) * x[(long)((int)q & 0xFFFFF) * D + lane];
    }
    long o = (long)row * D + lane;
    if (acc) { nxt[o] = sum; acc[o] += sum; }
    else __builtin_nontemporal_store(sum, &nxt[o]);
}

// ---------- Phase 3: gamma = dot of layer-mean embeddings ----------
__global__ void dot_kernel(const float* __restrict__ x0, const float* __restrict__ x1,
                           const float* __restrict__ x2, const float* __restrict__ x3,
                           const float* __restrict__ acc,
                           const int* __restrict__ users, const int* __restrict__ items,
                           float* __restrict__ out, int U, int B) {
    int wave = (blockIdx.x * blockDim.x + threadIdx.x) >> 6;
    int lane = threadIdx.x & 63;
    if (wave >= B) return;
    long ou = (long)users[wave] * D + lane;
    long oi = (long)(U + items[wave]) * D + lane;
    float su, si;
    if (acc) {
        su = acc[ou];
        si = acc[oi];
    } else {
        su = x0[ou] + x1[ou] + x2[ou] + x3[ou];
        si = x0[oi] + x1[oi] + x2[oi] + x3[oi];
    }
    float p = su * si;
    #pragma unroll
    for (int off = 32; off > 0; off >>= 1) p += __shfl_xor(p, off, 64);
    if (lane == 0) out[wave] = p * 0.0625f;
}

extern "C" void kernel_launch(void* const* d_in, const int* in_sizes, int n_in,
                              void* d_out, int out_size, void* d_ws, size_t ws_size,
                              hipStream_t stream) {
    const int*   users    = (const int*)  d_in[0];
    const int*   items    = (const int*)  d_in[1];
    const int*   g_rows   = (const int*)  d_in[2];
    const int*   g_cols   = (const int*)  d_in[3];
    const float* g_vals   = (const float*)d_in[4];
    const float* user_emb = (const float*)d_in[5];
    const float* item_emb = (const float*)d_in[6];
    const float* ent_emb  = (const float*)d_in[7];
    const float* rel_emb  = (const float*)d_in[8];
    const int*   kg_e     = (const int*)  d_in[9];
    const int*   kg_r     = (const int*)  d_in[10];
    const float* fc_W     = (const float*)d_in[11];
    const float* fc_b     = (const float*)d_in[12];
    float* out = (float*)d_out;

    int B       = in_sizes[0];
    int n_edges = in_sizes[2];
    int U       = in_sizes[5] / D;
    int I       = in_sizes[6] / D;
    int NE1     = in_sizes[7] / D;   // E_ENT + 1
    int NR      = in_sizes[8] / D;   // R + 1
    int K       = in_sizes[9] / I;
    int N  = U + I;
    int ND = N * D;
    int NB = (N + BROWS - 1) >> BSH;   // 586 buckets

    // deferred-acc mode needs 4 layer buffers; legacy needs 3 (x,y,acc)
    size_t small = (size_t)(2 * NR * D + NR + 3 * (NB + 1) + 2 * N) * 4 + 4096;
    size_t need_def = 4ul * ND * 4 + (size_t)n_edges * 8 + small;
    int deferred = (need_def <= ws_size);

    char* basep = (char*)d_ws;
    size_t woff = 0;
    auto alloc = [&](size_t bytes) -> char* {
        char* p = basep + woff;
        woff = (woff + bytes + 255) & ~(size_t)255;
        return p;
    };

    float *x0, *x1, *x2, *x3, *acc;
    long* etmp;
    if (deferred) {
        x0 = (float*)alloc((size_t)ND * 4);
        x1 = (float*)alloc((size_t)ND * 4);
        x2 = (float*)alloc((size_t)ND * 4);
        x3 = (float*)alloc((size_t)ND * 4);
        acc = nullptr;
        etmp = (long*)x2;               // x2+x3 span 38.4MB >= 32MB; build precedes layers
    } else {
        x0 = (float*)alloc((size_t)ND * 4);
        x1 = (float*)alloc((size_t)ND * 4);
        x2 = x0; x3 = x1;               // ping-pong
        acc = (float*)alloc((size_t)ND * 4);
        etmp = (long*)x0;               // x0+x1 span
    }
    float* w1r      = (float*)alloc((size_t)NR * D * 4);
    float* w2r      = (float*)alloc((size_t)NR * D * 4);
    float* br       = (float*)alloc((size_t)NR * 4);
    int*   bcnt     = (int*)  alloc((size_t)(NB + 1) * 4);
    int*   bstart   = (int*)  alloc((size_t)(NB + 1) * 4);
    int*   bfill    = (int*)  alloc((size_t)(NB + 1) * 4);
    int*   row_start= (int*)  alloc((size_t)N * 4);
    int*   cnt      = (int*)  alloc((size_t)N * 4);
    long*  edges    = (long*) alloc((size_t)n_edges * 8);

    // ---- CSR build (etmp occupies layer-buffer space; runs first) ----
    hipMemsetAsync(bcnt, 0, (size_t)(NB + 1) * 4, stream);
    bhist_kernel<<<512, 256, 0, stream>>>(g_rows, bcnt, n_edges, NB);
    bscan_kernel<<<1, MAXNB, 0, stream>>>(bcnt, bstart, bfill, NB, n_edges);
    part_kernel<<<512, 256, 0, stream>>>(g_rows, g_cols, g_vals, bfill, etmp, n_edges, NB);
    sort_kernel<<<NB, 256, 0, stream>>>(etmp, bstart, edges, row_start, cnt, N);

    // Phase 0 + 1: GAT
    relpre_kernel<<<NR, D, 0, stream>>>(fc_W, fc_b, rel_emb, w1r, w2r, br);
    gat_kernel<<<(I + 3) / 4, 256, 0, stream>>>(item_emb, ent_emb, kg_e, kg_r,
                                                w1r, w2r, br,
                                                x0 + (long)U * D, I, K, NE1 - 1);

    // Phase 2a: user half of x0 (+ acc init in legacy mode)
    if (deferred) {
        int n4 = U * D / 4;
        copyu_kernel<<<(n4 + 255) / 256, 256, 0, stream>>>(user_emb, x0, n4);
    } else {
        init_kernel<<<2048, 256, 0, stream>>>(user_emb, x0, acc, U * D, ND);
    }

    // Phase 2b: 3 LightGCN layers
    long total = (long)N * 64;
    int blocks = (int)((total + 255) / 256);
    spmv_kernel<<<blocks, 256, 0, stream>>>(edges, row_start, cnt, x0, x1, acc, N);
    spmv_kernel<<<blocks, 256, 0, stream>>>(edges, row_start, cnt, x1, x2, acc, N);
    spmv_kernel<<<blocks, 256, 0, stream>>>(edges, row_start, cnt, x2, x3, acc, N);

    // Phase 3: batch dot
    dot_kernel<<<(B + 3) / 4, 256, 0, stream>>>(x0, x1, x2, x3, acc, users, items, out, U, B);
}

// Round 6
// 544.047 us; speedup vs baseline: 1.3319x; 1.3319x over previous
//
#include <hip/hip_runtime.h>

#define D 64
#define NEG_INF -9e15f
#define MAXK 16
#define BSH 7                 // bucket = 128 rows
#define BROWS 128
#define MAXNB 1024
#define SCAP 7936             // LDS sort capacity (edges); bucket mean 6827, sigma 83

// ---------- Phase 0: relation-space precompute ----------
__global__ void relpre_kernel(const float* __restrict__ fc_W, const float* __restrict__ fc_b,
                              const float* __restrict__ rel_emb,
                              float* __restrict__ w1r, float* __restrict__ w2r,
                              float* __restrict__ br) {
    int r = blockIdx.x;
    int j = threadIdx.x;
    const float* rr = rel_emb + r * D;
    float s1 = 0.f, s2 = 0.f;
    for (int d = 0; d < D; ++d) {
        float rv = rr[d];
        s1 += fc_W[j * D + d] * rv;
        s2 += fc_W[(D + j) * D + d] * rv;
    }
    w1r[r * D + j] = s1;
    w2r[r * D + j] = s2;
    if (j == 0) {
        float sb = 0.f;
        for (int d = 0; d < D; ++d) sb += fc_b[d] * rr[d];
        br[r] = sb;
    }
}

// ---------- Phase 1: GAT item embeddings, K=16 specialized ----------
// One wave per item; lane = feature. Pass 1 issues all gathers + partial
// products (ILP), pass 2 does the 16 butterfly reductions + softmax.
__global__ void gat16_kernel(const float* __restrict__ item_emb, const float* __restrict__ ent_emb,
                             const int* __restrict__ kg_e, const int* __restrict__ kg_r,
                             const float* __restrict__ w1r, const float* __restrict__ w2r,
                             const float* __restrict__ br,
                             float* __restrict__ x_items, int I, int pad_id) {
    const int K = 16;
    int wave = (blockIdx.x * blockDim.x + threadIdx.x) >> 6;
    int lane = threadIdx.x & 63;
    if (wave >= I) return;
    int i = wave;
    float itemv = item_emb[i * D + lane];
    float entv[16], pp[16], brv[16];
    int eidx_[16];
    #pragma unroll
    for (int k = 0; k < K; ++k) {
        int eidx = kg_e[i * K + k];
        int r = kg_r[i * K + k];
        eidx_[k] = eidx;
        float ev = ent_emb[(long)eidx * D + lane];
        entv[k] = ev;
        pp[k] = itemv * w1r[r * D + lane] + ev * w2r[r * D + lane];
        brv[k] = br[r];
    }
    float e[16];
    #pragma unroll
    for (int k = 0; k < K; ++k) {
        float p = pp[k];
        #pragma unroll
        for (int off = 32; off > 0; off >>= 1) p += __shfl_xor(p, off, 64);
        p += brv[k];
        p = p > 0.f ? p : 0.2f * p;
        if (eidx_[k] == pad_id) p = NEG_INF;
        e[k] = p;
    }
    float m = e[0];
    #pragma unroll
    for (int k = 1; k < K; ++k) m = fmaxf(m, e[k]);
    float s = 0.f;
    float att[16];
    #pragma unroll
    for (int k = 0; k < K; ++k) { att[k] = expf(e[k] - m); s += att[k]; }
    float inv = 1.f / s;
    float o = itemv;
    #pragma unroll
    for (int k = 0; k < K; ++k) o += att[k] * inv * entv[k];
    x_items[(long)i * D + lane] = o;
}

// ---------- Phase 1 fallback: generic K ----------
__global__ void gat_kernel(const float* __restrict__ item_emb, const float* __restrict__ ent_emb,
                           const int* __restrict__ kg_e, const int* __restrict__ kg_r,
                           const float* __restrict__ w1r, const float* __restrict__ w2r,
                           const float* __restrict__ br,
                           float* __restrict__ x_items, int I, int K, int pad_id) {
    int wave = (blockIdx.x * blockDim.x + threadIdx.x) >> 6;
    int lane = threadIdx.x & 63;
    if (wave >= I) return;
    int i = wave;
    float itemv = item_emb[i * D + lane];
    float entv[MAXK];
    float e[MAXK];
    for (int k = 0; k < K; ++k) {
        int eidx = kg_e[i * K + k];
        int r = kg_r[i * K + k];
        float ev = ent_emb[(long)eidx * D + lane];
        entv[k] = ev;
        float p = itemv * w1r[r * D + lane] + ev * w2r[r * D + lane];
        #pragma unroll
        for (int off = 32; off > 0; off >>= 1) p += __shfl_xor(p, off, 64);
        p += br[r];
        p = p > 0.f ? p : 0.2f * p;
        if (eidx == pad_id) p = NEG_INF;
        e[k] = p;
    }
    float m = e[0];
    for (int k = 1; k < K; ++k) m = fmaxf(m, e[k]);
    float s = 0.f;
    float att[MAXK];
    for (int k = 0; k < K; ++k) { att[k] = expf(e[k] - m); s += att[k]; }
    float inv = 1.f / s;
    float o = itemv;
    for (int k = 0; k < K; ++k) o += att[k] * inv * entv[k];
    x_items[(long)i * D + lane] = o;
}

// ---------- init (deferred mode): copy user_emb -> x0 user half ----------
__global__ void copyu_kernel(const float* __restrict__ src, float* __restrict__ dst, int n4) {
    int i = blockIdx.x * blockDim.x + threadIdx.x;
    if (i < n4) ((float4*)dst)[i] = ((const float4*)src)[i];
}

// ---------- init (legacy mode): x users + acc = x ----------
__global__ void init_kernel(const float* __restrict__ user_emb,
                            float* __restrict__ x, float* __restrict__ acc,
                            int UD, int ND) {
    for (int idx = blockIdx.x * blockDim.x + threadIdx.x; idx < ND;
         idx += gridDim.x * blockDim.x) {
        float v = (idx < UD) ? user_emb[idx] : x[idx];
        x[idx] = v;
        acc[idx] = v;
    }
}

// ---------- Bucket histogram (LDS-staged) ----------
__global__ void bhist_kernel(const int* __restrict__ rows, int* __restrict__ bcnt,
                             int n_edges, int NB) {
    __shared__ int h[MAXNB];
    for (int i = threadIdx.x; i < NB; i += blockDim.x) h[i] = 0;
    __syncthreads();
    for (int e = blockIdx.x * blockDim.x + threadIdx.x; e < n_edges;
         e += gridDim.x * blockDim.x)
        atomicAdd(&h[rows[e] >> BSH], 1);
    __syncthreads();
    for (int i = threadIdx.x; i < NB; i += blockDim.x)
        if (h[i]) atomicAdd(&bcnt[i], h[i]);
}

// ---------- Bucket scan (single block; NB <= 1024) ----------
__global__ void bscan_kernel(const int* __restrict__ bcnt, int* __restrict__ bstart,
                             int* __restrict__ bfill, int NB, int n_edges) {
    __shared__ int tmp[MAXNB];
    int tid = threadIdx.x;
    int v = (tid < NB) ? bcnt[tid] : 0;
    tmp[tid] = v;
    __syncthreads();
    for (int off = 1; off < MAXNB; off <<= 1) {
        int t = (tid >= off) ? tmp[tid - off] : 0;
        __syncthreads();
        tmp[tid] += t;
        __syncthreads();
    }
    if (tid < NB) {
        int ex = tmp[tid] - v;
        bstart[tid] = ex;
        bfill[tid] = ex;
    }
    if (tid == 0) bstart[NB] = n_edges;
}

// ---------- Partition: per-block hist -> segment reserve -> direct write ----------
// etmp[pos] = (valbits<<32) | (row&127)<<20 | col    (NORMAL store: L2 absorbs
// the scatter and keeps the segment hot for sort_kernel — nt store here was
// the R4 regression: 126MB HBM writes + cold re-reads)
__global__ void part_kernel(const int* __restrict__ rows, const int* __restrict__ cols,
                            const float* __restrict__ vals,
                            int* __restrict__ bfill, long* __restrict__ etmp,
                            int n_edges, int NB) {
    __shared__ int h[MAXNB];
    __shared__ int base[MAXNB];
    __shared__ int off[MAXNB];
    int nb_blocks = gridDim.x;
    int c0 = (int)((long)n_edges * blockIdx.x / nb_blocks);
    int c1 = (int)((long)n_edges * (blockIdx.x + 1) / nb_blocks);
    for (int i = threadIdx.x; i < NB; i += blockDim.x) { h[i] = 0; off[i] = 0; }
    __syncthreads();
    for (int e = c0 + threadIdx.x; e < c1; e += blockDim.x)
        atomicAdd(&h[rows[e] >> BSH], 1);
    __syncthreads();
    for (int i = threadIdx.x; i < NB; i += blockDim.x)
        if (h[i]) base[i] = atomicAdd(&bfill[i], h[i]);
    __syncthreads();
    for (int e = c0 + threadIdx.x; e < c1; e += blockDim.x) {
        int r = rows[e];
        int b = r >> BSH;
        int pos = base[b] + atomicAdd(&off[b], 1);
        etmp[pos] = ((long)(unsigned)__float_as_int(vals[e]) << 32)
                  | (unsigned)(cols[e] | ((r & (BROWS - 1)) << 20));
    }
}

// ---------- In-bucket counting sort -> exact CSR ----------
__global__ __launch_bounds__(256) void
sort_kernel(const long* __restrict__ etmp, const int* __restrict__ bstart,
            long* __restrict__ edges, int* __restrict__ row_start,
            int* __restrict__ cnt, int N) {
    __shared__ long obuf[SCAP];
    __shared__ int h[BROWS];
    __shared__ int excl[BROWS];
    __shared__ int off[BROWS];
    int b = blockIdx.x;
    int s = bstart[b];
    int t = bstart[b + 1];
    int m = t - s;
    int tid = threadIdx.x;
    if (tid < BROWS) { h[tid] = 0; off[tid] = 0; }
    __syncthreads();
    for (int i = tid; i < m; i += 256)
        atomicAdd(&h[((int)etmp[s + i] >> 20) & (BROWS - 1)], 1);
    __syncthreads();
    if (tid < BROWS) excl[tid] = h[tid];
    __syncthreads();
    for (int o = 1; o < BROWS; o <<= 1) {
        int v = (tid < BROWS && tid >= o) ? excl[tid - o] : 0;
        __syncthreads();
        if (tid < BROWS) excl[tid] += v;
        __syncthreads();
    }
    int row0 = b << BSH;
    if (tid < BROWS) {
        int ex = excl[tid] - h[tid];       // exclusive
        excl[tid] = ex;
        int row = row0 + tid;
        if (row < N) { row_start[row] = s + ex; cnt[row] = h[tid]; }
    }
    __syncthreads();
    if (m <= SCAP) {
        for (int i = tid; i < m; i += 256) {
            long v = etmp[s + i];          // L2-hot second read
            int r = ((int)v >> 20) & (BROWS - 1);
            int pos = excl[r] + atomicAdd(&off[r], 1);
            obuf[pos] = (v & ~0xFFFFFFFFL) | (unsigned)((unsigned)v & 0xFFFFFu);
        }
        __syncthreads();
        for (int i = tid; i < m; i += 256) edges[s + i] = obuf[i];
    } else {
        for (int i = tid; i < m; i += 256) {
            long v = etmp[s + i];
            int r = ((int)v >> 20) & (BROWS - 1);
            int pos = s + excl[r] + atomicAdd(&off[r], 1);
            edges[pos] = (v & ~0xFFFFFFFFL) | (unsigned)((unsigned)v & 0xFFFFFu);
        }
    }
}

// ---------- Phase 2b: CSR SpMV, one wave per row ----------
// row/s/n made wave-uniform via readfirstlane -> edge loads can scalarize
// (s_load through K$), freeing VMEM issue slots for the 16 outstanding
// 256B x-row gathers per iteration.
__global__ __launch_bounds__(256) void
spmv_kernel(const long* __restrict__ edges, const int* __restrict__ row_start,
            const int* __restrict__ cnt, const float* __restrict__ x,
            float* __restrict__ nxt, float* __restrict__ acc, int N) {
    int wid = (int)((long)blockIdx.x * blockDim.x + threadIdx.x) >> 6;
    int row = __builtin_amdgcn_readfirstlane(wid);
    int lane = threadIdx.x & 63;
    if (row >= N) return;
    int s = __builtin_amdgcn_readfirstlane(row_start[row]);
    int n = __builtin_amdgcn_readfirstlane(cnt[row]);
    const long* ep = edges + s;
    float sum = 0.f;
    int e = 0;
    for (; e + 16 <= n; e += 16) {
        long q[16];
        float g[16];
        #pragma unroll
        for (int j = 0; j < 16; ++j) q[j] = ep[e + j];
        #pragma unroll
        for (int j = 0; j < 16; ++j) g[j] = x[(long)((int)q[j] & 0xFFFFF) * D + lane];
        #pragma unroll
        for (int j = 0; j < 16; ++j) sum += __int_as_float((int)(q[j] >> 32)) * g[j];
    }
    for (; e + 4 <= n; e += 4) {
        long q[4];
        float g[4];
        #pragma unroll
        for (int j = 0; j < 4; ++j) q[j] = ep[e + j];
        #pragma unroll
        for (int j = 0; j < 4; ++j) g[j] = x[(long)((int)q[j] & 0xFFFFF) * D + lane];
        #pragma unroll
        for (int j = 0; j < 4; ++j) sum += __int_as_float((int)(q[j] >> 32)) * g[j];
    }
    for (; e < n; ++e) {
        long q = ep[e];
        sum += __int_as_float((int)(q >> 32)) * x[(long)((int)q & 0xFFFFF) * D + lane];
    }
    long o = (long)row * D + lane;
    if (acc) { nxt[o] = sum; acc[o] += sum; }
    else __builtin_nontemporal_store(sum, &nxt[o]);
}

// ---------- Phase 3: gamma = dot of layer-mean embeddings ----------
__global__ void dot_kernel(const float* __restrict__ x0, const float* __restrict__ x1,
                           const float* __restrict__ x2, const float* __restrict__ x3,
                           const float* __restrict__ acc,
                           const int* __restrict__ users, const int* __restrict__ items,
                           float* __restrict__ out, int U, int B) {
    int wave = (blockIdx.x * blockDim.x + threadIdx.x) >> 6;
    int lane = threadIdx.x & 63;
    if (wave >= B) return;
    long ou = (long)users[wave] * D + lane;
    long oi = (long)(U + items[wave]) * D + lane;
    float su, si;
    if (acc) {
        su = acc[ou];
        si = acc[oi];
    } else {
        su = x0[ou] + x1[ou] + x2[ou] + x3[ou];
        si = x0[oi] + x1[oi] + x2[oi] + x3[oi];
    }
    float p = su * si;
    #pragma unroll
    for (int off = 32; off > 0; off >>= 1) p += __shfl_xor(p, off, 64);
    if (lane == 0) out[wave] = p * 0.0625f;
}

extern "C" void kernel_launch(void* const* d_in, const int* in_sizes, int n_in,
                              void* d_out, int out_size, void* d_ws, size_t ws_size,
                              hipStream_t stream) {
    const int*   users    = (const int*)  d_in[0];
    const int*   items    = (const int*)  d_in[1];
    const int*   g_rows   = (const int*)  d_in[2];
    const int*   g_cols   = (const int*)  d_in[3];
    const float* g_vals   = (const float*)d_in[4];
    const float* user_emb = (const float*)d_in[5];
    const float* item_emb = (const float*)d_in[6];
    const float* ent_emb  = (const float*)d_in[7];
    const float* rel_emb  = (const float*)d_in[8];
    const int*   kg_e     = (const int*)  d_in[9];
    const int*   kg_r     = (const int*)  d_in[10];
    const float* fc_W     = (const float*)d_in[11];
    const float* fc_b     = (const float*)d_in[12];
    float* out = (float*)d_out;

    int B       = in_sizes[0];
    int n_edges = in_sizes[2];
    int U       = in_sizes[5] / D;
    int I       = in_sizes[6] / D;
    int NE1     = in_sizes[7] / D;   // E_ENT + 1
    int NR      = in_sizes[8] / D;   // R + 1
    int K       = in_sizes[9] / I;
    int N  = U + I;
    int ND = N * D;
    int NB = (N + BROWS - 1) >> BSH;   // 586 buckets

    // deferred-acc mode needs 4 layer buffers; legacy needs 3 (x,y,acc)
    size_t small = (size_t)(2 * NR * D + NR + 3 * (NB + 1) + 2 * N) * 4 + 4096;
    size_t need_def = 4ul * ND * 4 + (size_t)n_edges * 8 + small;
    int deferred = (need_def <= ws_size);

    char* basep = (char*)d_ws;
    size_t woff = 0;
    auto alloc = [&](size_t bytes) -> char* {
        char* p = basep + woff;
        woff = (woff + bytes + 255) & ~(size_t)255;
        return p;
    };

    float *x0, *x1, *x2, *x3, *acc;
    long* etmp;
    if (deferred) {
        x0 = (float*)alloc((size_t)ND * 4);
        x1 = (float*)alloc((size_t)ND * 4);
        x2 = (float*)alloc((size_t)ND * 4);
        x3 = (float*)alloc((size_t)ND * 4);
        acc = nullptr;
        etmp = (long*)x2;               // x2+x3 span 38.4MB >= 32MB; build precedes layers
    } else {
        x0 = (float*)alloc((size_t)ND * 4);
        x1 = (float*)alloc((size_t)ND * 4);
        x2 = x0; x3 = x1;               // ping-pong
        acc = (float*)alloc((size_t)ND * 4);
        etmp = (long*)x0;               // x0+x1 span
    }
    float* w1r      = (float*)alloc((size_t)NR * D * 4);
    float* w2r      = (float*)alloc((size_t)NR * D * 4);
    float* br       = (float*)alloc((size_t)NR * 4);
    int*   bcnt     = (int*)  alloc((size_t)(NB + 1) * 4);
    int*   bstart   = (int*)  alloc((size_t)(NB + 1) * 4);
    int*   bfill    = (int*)  alloc((size_t)(NB + 1) * 4);
    int*   row_start= (int*)  alloc((size_t)N * 4);
    int*   cnt      = (int*)  alloc((size_t)N * 4);
    long*  edges    = (long*) alloc((size_t)n_edges * 8);

    // ---- CSR build (etmp occupies layer-buffer space; runs first) ----
    hipMemsetAsync(bcnt, 0, (size_t)(NB + 1) * 4, stream);
    bhist_kernel<<<512, 256, 0, stream>>>(g_rows, bcnt, n_edges, NB);
    bscan_kernel<<<1, MAXNB, 0, stream>>>(bcnt, bstart, bfill, NB, n_edges);
    part_kernel<<<512, 256, 0, stream>>>(g_rows, g_cols, g_vals, bfill, etmp, n_edges, NB);
    sort_kernel<<<NB, 256, 0, stream>>>(etmp, bstart, edges, row_start, cnt, N);

    // Phase 0 + 1: GAT
    relpre_kernel<<<NR, D, 0, stream>>>(fc_W, fc_b, rel_emb, w1r, w2r, br);
    if (K == 16) {
        gat16_kernel<<<(I + 3) / 4, 256, 0, stream>>>(item_emb, ent_emb, kg_e, kg_r,
                                                      w1r, w2r, br,
                                                      x0 + (long)U * D, I, NE1 - 1);
    } else {
        gat_kernel<<<(I + 3) / 4, 256, 0, stream>>>(item_emb, ent_emb, kg_e, kg_r,
                                                    w1r, w2r, br,
                                                    x0 + (long)U * D, I, K, NE1 - 1);
    }

    // Phase 2a: user half of x0 (+ acc init in legacy mode)
    if (deferred) {
        int n4 = U * D / 4;
        copyu_kernel<<<(n4 + 255) / 256, 256, 0, stream>>>(user_emb, x0, n4);
    } else {
        init_kernel<<<2048, 256, 0, stream>>>(user_emb, x0, acc, U * D, ND);
    }

    // Phase 2b: 3 LightGCN layers
    long total = (long)N * 64;
    int blocks = (int)((total + 255) / 256);
    spmv_kernel<<<blocks, 256, 0, stream>>>(edges, row_start, cnt, x0, x1, acc, N);
    spmv_kernel<<<blocks, 256, 0, stream>>>(edges, row_start, cnt, x1, x2, acc, N);
    spmv_kernel<<<blocks, 256, 0, stream>>>(edges, row_start, cnt, x2, x3, acc, N);

    // Phase 3: batch dot
    dot_kernel<<<(B + 3) / 4, 256, 0, stream>>>(x0, x1, x2, x3, acc, users, items, out, U, B);
}

// Round 7
// 475.942 us; speedup vs baseline: 1.5225x; 1.1431x over previous
//
#include <hip/hip_runtime.h>

#define D 64
#define NEG_INF -9e15f
#define MAXK 16
#define BSH 6                 // bucket = 64 rows
#define BROWS 64
#define MAXNB 2048
#define SCAP 4096             // LDS sort capacity; bucket mean 3413, sigma 58 (+11s)

// ---------- Phase 0: relation-space precompute ----------
__global__ void relpre_kernel(const float* __restrict__ fc_W, const float* __restrict__ fc_b,
                              const float* __restrict__ rel_emb,
                              float* __restrict__ w1r, float* __restrict__ w2r,
                              float* __restrict__ br) {
    int r = blockIdx.x;
    int j = threadIdx.x;
    const float* rr = rel_emb + r * D;
    float s1 = 0.f, s2 = 0.f;
    for (int d = 0; d < D; ++d) {
        float rv = rr[d];
        s1 += fc_W[j * D + d] * rv;
        s2 += fc_W[(D + j) * D + d] * rv;
    }
    w1r[r * D + j] = s1;
    w2r[r * D + j] = s2;
    if (j == 0) {
        float sb = 0.f;
        for (int d = 0; d < D; ++d) sb += fc_b[d] * rr[d];
        br[r] = sb;
    }
}

// ---------- Phase 1: GAT item embeddings, K=16 specialized ----------
__global__ void gat16_kernel(const float* __restrict__ item_emb, const float* __restrict__ ent_emb,
                             const int* __restrict__ kg_e, const int* __restrict__ kg_r,
                             const float* __restrict__ w1r, const float* __restrict__ w2r,
                             const float* __restrict__ br,
                             float* __restrict__ x_items, int I, int pad_id) {
    const int K = 16;
    int wave = (blockIdx.x * blockDim.x + threadIdx.x) >> 6;
    int lane = threadIdx.x & 63;
    if (wave >= I) return;
    int i = wave;
    float itemv = item_emb[i * D + lane];
    float entv[16], pp[16], brv[16];
    int eidx_[16];
    #pragma unroll
    for (int k = 0; k < K; ++k) {
        int eidx = kg_e[i * K + k];
        int r = kg_r[i * K + k];
        eidx_[k] = eidx;
        float ev = ent_emb[(long)eidx * D + lane];
        entv[k] = ev;
        pp[k] = itemv * w1r[r * D + lane] + ev * w2r[r * D + lane];
        brv[k] = br[r];
    }
    float e[16];
    #pragma unroll
    for (int k = 0; k < K; ++k) {
        float p = pp[k];
        #pragma unroll
        for (int off = 32; off > 0; off >>= 1) p += __shfl_xor(p, off, 64);
        p += brv[k];
        p = p > 0.f ? p : 0.2f * p;
        if (eidx_[k] == pad_id) p = NEG_INF;
        e[k] = p;
    }
    float m = e[0];
    #pragma unroll
    for (int k = 1; k < K; ++k) m = fmaxf(m, e[k]);
    float s = 0.f;
    float att[16];
    #pragma unroll
    for (int k = 0; k < K; ++k) { att[k] = expf(e[k] - m); s += att[k]; }
    float inv = 1.f / s;
    float o = itemv;
    #pragma unroll
    for (int k = 0; k < K; ++k) o += att[k] * inv * entv[k];
    x_items[(long)i * D + lane] = o;
}

// ---------- Phase 1 fallback: generic K ----------
__global__ void gat_kernel(const float* __restrict__ item_emb, const float* __restrict__ ent_emb,
                           const int* __restrict__ kg_e, const int* __restrict__ kg_r,
                           const float* __restrict__ w1r, const float* __restrict__ w2r,
                           const float* __restrict__ br,
                           float* __restrict__ x_items, int I, int K, int pad_id) {
    int wave = (blockIdx.x * blockDim.x + threadIdx.x) >> 6;
    int lane = threadIdx.x & 63;
    if (wave >= I) return;
    int i = wave;
    float itemv = item_emb[i * D + lane];
    float entv[MAXK];
    float e[MAXK];
    for (int k = 0; k < K; ++k) {
        int eidx = kg_e[i * K + k];
        int r = kg_r[i * K + k];
        float ev = ent_emb[(long)eidx * D + lane];
        entv[k] = ev;
        float p = itemv * w1r[r * D + lane] + ev * w2r[r * D + lane];
        #pragma unroll
        for (int off = 32; off > 0; off >>= 1) p += __shfl_xor(p, off, 64);
        p += br[r];
        p = p > 0.f ? p : 0.2f * p;
        if (eidx == pad_id) p = NEG_INF;
        e[k] = p;
    }
    float m = e[0];
    for (int k = 1; k < K; ++k) m = fmaxf(m, e[k]);
    float s = 0.f;
    float att[MAXK];
    for (int k = 0; k < K; ++k) { att[k] = expf(e[k] - m); s += att[k]; }
    float inv = 1.f / s;
    float o = itemv;
    for (int k = 0; k < K; ++k) o += att[k] * inv * entv[k];
    x_items[(long)i * D + lane] = o;
}

// ---------- init (deferred mode): copy user_emb -> x0 user half ----------
__global__ void copyu_kernel(const float* __restrict__ src, float* __restrict__ dst, int n4) {
    int i = blockIdx.x * blockDim.x + threadIdx.x;
    if (i < n4) ((float4*)dst)[i] = ((const float4*)src)[i];
}

// ---------- init (legacy mode): x users + acc = x ----------
__global__ void init_kernel(const float* __restrict__ user_emb,
                            float* __restrict__ x, float* __restrict__ acc,
                            int UD, int ND) {
    for (int idx = blockIdx.x * blockDim.x + threadIdx.x; idx < ND;
         idx += gridDim.x * blockDim.x) {
        float v = (idx < UD) ? user_emb[idx] : x[idx];
        x[idx] = v;
        acc[idx] = v;
    }
}

// ---------- Mark batch rows for sparse layer 3 ----------
__global__ void mark_kernel(const int* __restrict__ users, const int* __restrict__ items,
                            int* __restrict__ flags, int U, int B) {
    int i = blockIdx.x * blockDim.x + threadIdx.x;
    if (i < B) {
        flags[users[i]] = 1;
        flags[U + items[i]] = 1;
    }
}

// ---------- Bucket histogram (LDS-staged) ----------
__global__ void bhist_kernel(const int* __restrict__ rows, int* __restrict__ bcnt,
                             int n_edges, int NB) {
    __shared__ int h[MAXNB];
    for (int i = threadIdx.x; i < NB; i += blockDim.x) h[i] = 0;
    __syncthreads();
    for (int e = blockIdx.x * blockDim.x + threadIdx.x; e < n_edges;
         e += gridDim.x * blockDim.x)
        atomicAdd(&h[rows[e] >> BSH], 1);
    __syncthreads();
    for (int i = threadIdx.x; i < NB; i += blockDim.x)
        if (h[i]) atomicAdd(&bcnt[i], h[i]);
}

// ---------- Bucket scan (single block, 1024 thr, up to 2048 entries) ----------
__global__ void bscan_kernel(const int* __restrict__ bcnt, int* __restrict__ bstart,
                             int* __restrict__ bfill, int NB, int n_edges) {
    __shared__ int bufA[MAXNB];
    __shared__ int bufB[MAXNB];
    int tid = threadIdx.x;
    int v0 = (tid < NB) ? bcnt[tid] : 0;
    int v1 = (tid + 1024 < NB) ? bcnt[tid + 1024] : 0;
    bufA[tid] = v0;
    bufA[tid + 1024] = v1;
    __syncthreads();
    int* src = bufA;
    int* dst = bufB;
    for (int off = 1; off < MAXNB; off <<= 1) {
        int j0 = tid, j1 = tid + 1024;
        dst[j0] = src[j0] + (j0 >= off ? src[j0 - off] : 0);
        dst[j1] = src[j1] + (j1 >= off ? src[j1 - off] : 0);
        __syncthreads();
        int* t = src; src = dst; dst = t;
    }
    if (tid < NB)        { int ex = src[tid] - v0;        bstart[tid] = ex;        bfill[tid] = ex; }
    if (tid + 1024 < NB) { int ex = src[tid + 1024] - v1; bstart[tid + 1024] = ex; bfill[tid + 1024] = ex; }
    if (tid == 0) bstart[NB] = n_edges;
}

// ---------- Partition: per-block hist -> segment reserve -> direct write ----------
// etmp[pos] = (valbits<<32) | (row&63)<<20 | col   (normal stores: L2 absorbs)
__global__ void part_kernel(const int* __restrict__ rows, const int* __restrict__ cols,
                            const float* __restrict__ vals,
                            int* __restrict__ bfill, long* __restrict__ etmp,
                            int n_edges, int NB) {
    __shared__ int h[MAXNB];
    __shared__ int base[MAXNB];
    __shared__ int off[MAXNB];
    int nb_blocks = gridDim.x;
    int c0 = (int)((long)n_edges * blockIdx.x / nb_blocks);
    int c1 = (int)((long)n_edges * (blockIdx.x + 1) / nb_blocks);
    for (int i = threadIdx.x; i < NB; i += blockDim.x) { h[i] = 0; off[i] = 0; }
    __syncthreads();
    for (int e = c0 + threadIdx.x; e < c1; e += blockDim.x)
        atomicAdd(&h[rows[e] >> BSH], 1);
    __syncthreads();
    for (int i = threadIdx.x; i < NB; i += blockDim.x)
        if (h[i]) base[i] = atomicAdd(&bfill[i], h[i]);
    __syncthreads();
    for (int e = c0 + threadIdx.x; e < c1; e += blockDim.x) {
        int r = rows[e];
        int b = r >> BSH;
        int pos = base[b] + atomicAdd(&off[b], 1);
        etmp[pos] = ((long)(unsigned)__float_as_int(vals[e]) << 32)
                  | (unsigned)(cols[e] | ((r & (BROWS - 1)) << 20));
    }
}

// ---------- In-bucket counting sort -> exact CSR ----------
// obuf 32KB -> 4 blocks/CU (vs 2 at 62KB), 1172 blocks.
__global__ __launch_bounds__(256) void
sort_kernel(const long* __restrict__ etmp, const int* __restrict__ bstart,
            long* __restrict__ edges, int* __restrict__ row_start,
            int* __restrict__ cnt, int N) {
    __shared__ long obuf[SCAP];
    __shared__ int h[BROWS];
    __shared__ int excl[BROWS];
    __shared__ int off[BROWS];
    int b = blockIdx.x;
    int s = bstart[b];
    int t = bstart[b + 1];
    int m = t - s;
    int tid = threadIdx.x;
    if (tid < BROWS) { h[tid] = 0; off[tid] = 0; }
    __syncthreads();
    for (int i = tid; i < m; i += 256)
        atomicAdd(&h[((int)etmp[s + i] >> 20) & (BROWS - 1)], 1);
    __syncthreads();
    if (tid < BROWS) excl[tid] = h[tid];
    __syncthreads();
    for (int o = 1; o < BROWS; o <<= 1) {
        int v = (tid < BROWS && tid >= o) ? excl[tid - o] : 0;
        __syncthreads();
        if (tid < BROWS) excl[tid] += v;
        __syncthreads();
    }
    int row0 = b << BSH;
    if (tid < BROWS) {
        int ex = excl[tid] - h[tid];       // exclusive
        excl[tid] = ex;
        int row = row0 + tid;
        if (row < N) { row_start[row] = s + ex; cnt[row] = h[tid]; }
    }
    __syncthreads();
    if (m <= SCAP) {
        for (int i = tid; i < m; i += 256) {
            long v = etmp[s + i];          // L2-hot second read
            int r = ((int)v >> 20) & (BROWS - 1);
            int pos = excl[r] + atomicAdd(&off[r], 1);
            obuf[pos] = (v & ~0xFFFFFFFFL) | (unsigned)((unsigned)v & 0xFFFFFu);
        }
        __syncthreads();
        for (int i = tid; i < m; i += 256) edges[s + i] = obuf[i];
    } else {
        for (int i = tid; i < m; i += 256) {
            long v = etmp[s + i];
            int r = ((int)v >> 20) & (BROWS - 1);
            int pos = s + excl[r] + atomicAdd(&off[r], 1);
            edges[pos] = (v & ~0xFFFFFFFFL) | (unsigned)((unsigned)v & 0xFFFFFu);
        }
    }
}

// ---------- Phase 2b: CSR SpMV, one wave per row ----------
// Wave-uniform row via readfirstlane -> edge loads scalarize (s_load / K$),
// VMEM pipe free for the 16 outstanding 256B x-row gathers.
// flags != nullptr: compute only flagged rows (sparse layer 3).
__global__ __launch_bounds__(256) void
spmv_kernel(const long* __restrict__ edges, const int* __restrict__ row_start,
            const int* __restrict__ cnt, const float* __restrict__ x,
            float* __restrict__ nxt, float* __restrict__ acc,
            const int* __restrict__ flags, int N) {
    int wid = (int)((long)blockIdx.x * blockDim.x + threadIdx.x) >> 6;
    int row = __builtin_amdgcn_readfirstlane(wid);
    int lane = threadIdx.x & 63;
    if (row >= N) return;
    if (flags && !flags[row]) return;      // wave-uniform scalar branch
    int s = __builtin_amdgcn_readfirstlane(row_start[row]);
    int n = __builtin_amdgcn_readfirstlane(cnt[row]);
    const long* ep = edges + s;
    float sum = 0.f;
    int e = 0;
    for (; e + 16 <= n; e += 16) {
        long q[16];
        float g[16];
        #pragma unroll
        for (int j = 0; j < 16; ++j) q[j] = ep[e + j];
        #pragma unroll
        for (int j = 0; j < 16; ++j) g[j] = x[(long)((int)q[j] & 0xFFFFF) * D + lane];
        #pragma unroll
        for (int j = 0; j < 16; ++j) sum += __int_as_float((int)(q[j] >> 32)) * g[j];
    }
    for (; e + 4 <= n; e += 4) {
        long q[4];
        float g[4];
        #pragma unroll
        for (int j = 0; j < 4; ++j) q[j] = ep[e + j];
        #pragma unroll
        for (int j = 0; j < 4; ++j) g[j] = x[(long)((int)q[j] & 0xFFFFF) * D + lane];
        #pragma unroll
        for (int j = 0; j < 4; ++j) sum += __int_as_float((int)(q[j] >> 32)) * g[j];
    }
    for (; e < n; ++e) {
        long q = ep[e];
        sum += __int_as_float((int)(q >> 32)) * x[(long)((int)q & 0xFFFFF) * D + lane];
    }
    long o = (long)row * D + lane;
    if (acc) { nxt[o] = sum; acc[o] += sum; }
    else __builtin_nontemporal_store(sum, &nxt[o]);
}

// ---------- Phase 3: gamma = dot of layer-mean embeddings ----------
__global__ void dot_kernel(const float* __restrict__ x0, const float* __restrict__ x1,
                           const float* __restrict__ x2, const float* __restrict__ x3,
                           const float* __restrict__ acc,
                           const int* __restrict__ users, const int* __restrict__ items,
                           float* __restrict__ out, int U, int B) {
    int wave = (blockIdx.x * blockDim.x + threadIdx.x) >> 6;
    int lane = threadIdx.x & 63;
    if (wave >= B) return;
    long ou = (long)users[wave] * D + lane;
    long oi = (long)(U + items[wave]) * D + lane;
    float su, si;
    if (acc) {
        su = acc[ou];
        si = acc[oi];
    } else {
        su = x0[ou] + x1[ou] + x2[ou] + x3[ou];
        si = x0[oi] + x1[oi] + x2[oi] + x3[oi];
    }
    float p = su * si;
    #pragma unroll
    for (int off = 32; off > 0; off >>= 1) p += __shfl_xor(p, off, 64);
    if (lane == 0) out[wave] = p * 0.0625f;
}

extern "C" void kernel_launch(void* const* d_in, const int* in_sizes, int n_in,
                              void* d_out, int out_size, void* d_ws, size_t ws_size,
                              hipStream_t stream) {
    const int*   users    = (const int*)  d_in[0];
    const int*   items    = (const int*)  d_in[1];
    const int*   g_rows   = (const int*)  d_in[2];
    const int*   g_cols   = (const int*)  d_in[3];
    const float* g_vals   = (const float*)d_in[4];
    const float* user_emb = (const float*)d_in[5];
    const float* item_emb = (const float*)d_in[6];
    const float* ent_emb  = (const float*)d_in[7];
    const float* rel_emb  = (const float*)d_in[8];
    const int*   kg_e     = (const int*)  d_in[9];
    const int*   kg_r     = (const int*)  d_in[10];
    const float* fc_W     = (const float*)d_in[11];
    const float* fc_b     = (const float*)d_in[12];
    float* out = (float*)d_out;

    int B       = in_sizes[0];
    int n_edges = in_sizes[2];
    int U       = in_sizes[5] / D;
    int I       = in_sizes[6] / D;
    int NE1     = in_sizes[7] / D;   // E_ENT + 1
    int NR      = in_sizes[8] / D;   // R + 1
    int K       = in_sizes[9] / I;
    int N  = U + I;
    int ND = N * D;
    int NB = (N + BROWS - 1) >> BSH;   // 1172 buckets (must be <= MAXNB)

    // deferred-acc mode needs 4 layer buffers; legacy needs 3 (x,y,acc)
    size_t small = (size_t)(2 * NR * D + NR + 3 * (NB + 1) + 3 * N) * 4 + 8192;
    size_t need_def = 4ul * ND * 4 + (size_t)n_edges * 8 + small;
    int deferred = (need_def <= ws_size);

    char* basep = (char*)d_ws;
    size_t woff = 0;
    auto alloc = [&](size_t bytes) -> char* {
        char* p = basep + woff;
        woff = (woff + bytes + 255) & ~(size_t)255;
        return p;
    };

    float *x0, *x1, *x2, *x3, *acc;
    long* etmp;
    if (deferred) {
        x0 = (float*)alloc((size_t)ND * 4);
        x1 = (float*)alloc((size_t)ND * 4);
        x2 = (float*)alloc((size_t)ND * 4);
        x3 = (float*)alloc((size_t)ND * 4);
        acc = nullptr;
        etmp = (long*)x2;               // x2+x3 span 38.4MB >= 32MB; build precedes layers
    } else {
        x0 = (float*)alloc((size_t)ND * 4);
        x1 = (float*)alloc((size_t)ND * 4);
        x2 = x0; x3 = x1;               // ping-pong
        acc = (float*)alloc((size_t)ND * 4);
        etmp = (long*)x0;               // x0+x1 span
    }
    float* w1r      = (float*)alloc((size_t)NR * D * 4);
    float* w2r      = (float*)alloc((size_t)NR * D * 4);
    float* br       = (float*)alloc((size_t)NR * 4);
    int*   bcnt     = (int*)  alloc((size_t)(NB + 1) * 4);
    int*   bstart   = (int*)  alloc((size_t)(NB + 1) * 4);
    int*   bfill    = (int*)  alloc((size_t)(NB + 1) * 4);
    int*   row_start= (int*)  alloc((size_t)N * 4);
    int*   cnt      = (int*)  alloc((size_t)N * 4);
    int*   flags    = (int*)  alloc((size_t)N * 4);
    long*  edges    = (long*) alloc((size_t)n_edges * 8);

    // ---- CSR build (etmp occupies layer-buffer space; runs first) ----
    hipMemsetAsync(bcnt, 0, (size_t)(NB + 1) * 4, stream);
    bhist_kernel<<<512, 256, 0, stream>>>(g_rows, bcnt, n_edges, NB);
    bscan_kernel<<<1, 1024, 0, stream>>>(bcnt, bstart, bfill, NB, n_edges);
    part_kernel<<<512, 256, 0, stream>>>(g_rows, g_cols, g_vals, bfill, etmp, n_edges, NB);
    sort_kernel<<<NB, 256, 0, stream>>>(etmp, bstart, edges, row_start, cnt, N);

    // ---- batch-row flags for sparse layer 3 ----
    hipMemsetAsync(flags, 0, (size_t)N * 4, stream);
    mark_kernel<<<(B + 255) / 256, 256, 0, stream>>>(users, items, flags, U, B);

    // Phase 0 + 1: GAT
    relpre_kernel<<<NR, D, 0, stream>>>(fc_W, fc_b, rel_emb, w1r, w2r, br);
    if (K == 16) {
        gat16_kernel<<<(I + 3) / 4, 256, 0, stream>>>(item_emb, ent_emb, kg_e, kg_r,
                                                      w1r, w2r, br,
                                                      x0 + (long)U * D, I, NE1 - 1);
    } else {
        gat_kernel<<<(I + 3) / 4, 256, 0, stream>>>(item_emb, ent_emb, kg_e, kg_r,
                                                    w1r, w2r, br,
                                                    x0 + (long)U * D, I, K, NE1 - 1);
    }

    // Phase 2a: user half of x0 (+ acc init in legacy mode)
    if (deferred) {
        int n4 = U * D / 4;
        copyu_kernel<<<(n4 + 255) / 256, 256, 0, stream>>>(user_emb, x0, n4);
    } else {
        init_kernel<<<2048, 256, 0, stream>>>(user_emb, x0, acc, U * D, ND);
    }

    // Phase 2b: LightGCN layers 1-2 full, layer 3 sparse (batch rows only)
    long total = (long)N * 64;
    int blocks = (int)((total + 255) / 256);
    spmv_kernel<<<blocks, 256, 0, stream>>>(edges, row_start, cnt, x0, x1, acc, nullptr, N);
    spmv_kernel<<<blocks, 256, 0, stream>>>(edges, row_start, cnt, x1, x2, acc, nullptr, N);
    spmv_kernel<<<blocks, 256, 0, stream>>>(edges, row_start, cnt, x2, x3, acc, flags, N);

    // Phase 3: batch dot
    dot_kernel<<<(B + 3) / 4, 256, 0, stream>>>(x0, x1, x2, x3, acc, users, items, out, U, B);
}